// Round 5
// baseline (810.309 us; speedup 1.0000x reference)
//
#include <hip/hip_runtime.h>

// EGNN fused layer, MI355X gfx950. Round 5.
// R4 failed correctness (absmax 435, node path). Two suspects, both fixed:
//  (1) readfirstlane(float) may value-convert float->int (not bitcast) ->
//      We1/be1 corrupted -> s garbage. Fix: plain per-lane loads (R3 style).
//  (2) ws footprint grew to 19.3 MB (unit[] precompute); weight tables at
//      19.2 MB may be OOB. Fix: compute unit vectors in-kernel into a 2 KB
//      double-buffered LDS array (pipelined, tid<64 slice of staging phase);
//      ws back to R3's proven 6.48 MB.
// Kept from R4: double-buffered mlds prefetch pipeline, lgkm-only barriers
// (2/tile), per-wave coord atomics (no part_l reduction), single fused prep.

#define NN 50000
#define NE 800000
#define NDIM 64
#define HDIM 128
#define NTILES (NE / 64)      // 12500 exact
#define MSTRIDE 168           // m_input LDS row stride (ushort): 160 + 8 pad
#define HSTRIDE 136           // hidden LDS row stride (ushort): 128 + 8 pad
#define NH (NN * NDIM)
#define NX (NN * 3)

// ws layout (bytes) — identical to R3 (proven safe)
#define WS_HBF   0            // ushort[NN*64]   6,400,000
#define WS_WN1P  6400000      // ushort[160*128]    40,960
#define WS_WC1P  6440960      // ushort[160*128]    40,960
#define WS_BN1P  6481920      // float[128]            512
#define WS_BC1P  6482432      // float[128]            512

typedef __bf16 bf16x8 __attribute__((ext_vector_type(8)));
typedef float f32x4 __attribute__((ext_vector_type(4)));
typedef unsigned short ushort8 __attribute__((ext_vector_type(8)));
typedef unsigned short ushort4v __attribute__((ext_vector_type(4)));

// lgkm-only barrier: orders cross-wave LDS, leaves vmcnt (atomics, prefetch
// loads) in flight. Correct: all cross-wave data flows through LDS; VMEM is
// read-only input or write-only atomic accumulation, never read back.
#define LGKM_BARRIER() asm volatile("s_waitcnt lgkmcnt(0)\n\ts_barrier" ::: "memory")

__device__ __forceinline__ unsigned short f2bf(float f) {
    union { float f; unsigned int u; } c; c.f = f;
    unsigned int r = c.u + 0x7fffu + ((c.u >> 16) & 1u);   // RNE
    return (unsigned short)(r >> 16);
}
__device__ __forceinline__ unsigned int pk2bf(float a, float b) {
    return (unsigned int)f2bf(a) | ((unsigned int)f2bf(b) << 16);
}
__device__ __forceinline__ float silu(float v) {
    return v * __builtin_amdgcn_rcpf(1.0f + __expf(-v));
}
__device__ __forceinline__ bf16x8 ld_frag(const unsigned short* p) {
    union { ushort8 u; bf16x8 v; } c;
    c.u = *(const ushort8*)p;
    return c.v;
}
__device__ __forceinline__ bf16x8 mk_frag(const unsigned short* u) {
    union { ushort8 uu; bf16x8 v; } c;
#pragma unroll
    for (int j = 0; j < 8; ++j) c.uu[j] = u[j];
    return c.v;
}

// One fused prep kernel:
//  gid [0, 837500):           out init (h|x) as float4; first 800000 also hbf
//  gid [837500, 857980):      fused bf16 weights + biases
__global__ void prep_all(
    const float* __restrict__ h, const float* __restrict__ x,
    const float* __restrict__ We2, const float* __restrict__ be2,
    const float* __restrict__ Wn1, const float* __restrict__ bn1,
    const float* __restrict__ Wc1, const float* __restrict__ bc1,
    float* __restrict__ out, unsigned short* __restrict__ hbf,
    unsigned short* __restrict__ wn1p, unsigned short* __restrict__ wc1p,
    float* __restrict__ bn1p, float* __restrict__ bc1p) {
    int gid = blockIdx.x * 256 + threadIdx.x;
    if (gid < 837500) {
        if (gid < 800000) {
            float4 v = ((const float4*)h)[gid];
            ((float4*)out)[gid] = v;
            ushort4v u = { f2bf(v.x), f2bf(v.y), f2bf(v.z), f2bf(v.w) };
            ((ushort4v*)hbf)[gid] = u;
        } else {
            ((float4*)out)[gid] = ((const float4*)x)[gid - 800000];
        }
    } else if (gid < 837500 + 20480) {
        int idx = gid - 837500;
        int k = idx >> 7, n = idx & 127;
        float vn, vc;
        if (k < 128) {
            vn = Wn1[k * HDIM + n];
            vc = Wc1[k * HDIM + n];
        } else {
            int i = k - 128;
            float sn = 0.0f, sc = 0.0f;
            for (int j = 0; j < 32; ++j) {
                float wv = We2[i * 32 + j];
                sn += wv * Wn1[(128 + j) * HDIM + n];
                sc += wv * Wc1[(128 + j) * HDIM + n];
            }
            vn = sn; vc = sc;
        }
        wn1p[idx] = f2bf(vn);
        wc1p[idx] = f2bf(vc);
        if (idx < 128) {
            float sn = bn1[idx], sc = bc1[idx];
            for (int j = 0; j < 32; ++j) {
                sn += be2[j] * Wn1[(128 + j) * HDIM + idx];
                sc += be2[j] * Wc1[(128 + j) * HDIM + idx];
            }
            bn1p[idx] = sn;
            bc1p[idx] = sc;
        }
    }
}

__global__ __launch_bounds__(256, 2) void egnn_edges(
    const unsigned short* __restrict__ hbf, const float* __restrict__ x,
    const int* __restrict__ srcg, const int* __restrict__ dstg,
    const float* __restrict__ dist,
    const float* __restrict__ We1, const float* __restrict__ be1,
    const unsigned short* __restrict__ wn1p, const float* __restrict__ bn1p,
    const float* __restrict__ Wn2, const float* __restrict__ bn2,
    const unsigned short* __restrict__ wc1p, const float* __restrict__ bc1p,
    const float* __restrict__ Wc2,
    float* __restrict__ outh, float* __restrict__ outx) {

    __shared__ __align__(16) unsigned short mlds[2][64 * MSTRIDE];  // 43.0 KB
    __shared__ __align__(16) unsigned short hl[64 * HSTRIDE];       // 17.4 KB
    __shared__ int dst_l[2][64];
    __shared__ float4 unit_l[2][64];                                // 2.0 KB

    const int tid  = threadIdx.x;
    const int w    = tid >> 6;
    const int lane = tid & 63;
    const int l15  = lane & 15;
    const int quad = lane >> 4;
    const int c8   = tid & 7;        // staging column chunk
    const int sub  = tid >> 3;       // staging edge row (0..31)
    // butterfly output: this lane ends with coord partial for this edge
    const int bedge = ((l15 >> 2) << 4) + (quad << 2) + (l15 & 3);

    // ---- one-time: B-fragments to registers ----
    bf16x8 wn1f[5][2], wc1f[5][2];
#pragma unroll
    for (int kc = 0; kc < 5; ++kc) {
#pragma unroll
        for (int nt = 0; nt < 2; ++nt) {
            unsigned short un_[8], uc_[8];
            const int n = w * 32 + l15 * 2 + nt;
#pragma unroll
            for (int j = 0; j < 8; ++j) {
                const int k = kc * 32 + quad * 8 + j;
                un_[j] = wn1p[k * HDIM + n];
                uc_[j] = wc1p[k * HDIM + n];
            }
            wn1f[kc][nt] = mk_frag(un_);
            wc1f[kc][nt] = mk_frag(uc_);
        }
    }
    bf16x8 wn2f[4];
#pragma unroll
    for (int kc = 0; kc < 4; ++kc) {
        unsigned short u[8];
        const int n = w * 16 + l15;
#pragma unroll
        for (int j = 0; j < 8; ++j) {
            const int k = kc * 32 + quad * 8 + j;
            u[j] = f2bf(Wn2[k * NDIM + n]);
        }
        wn2f[kc] = mk_frag(u);
    }
    // edge-MLP layer-1 weights: plain per-lane loads (NO readfirstlane — the
    // builtin may value-convert float->int; this was R4's numeric corruption)
    float we1r[8], be1r[8];
#pragma unroll
    for (int j = 0; j < 8; ++j) {
        we1r[j] = We1[w * 8 + j];
        be1r[j] = be1[w * 8 + j];
    }
    const float biasN0 = bn1p[w * 32 + l15 * 2];
    const float biasN1 = bn1p[w * 32 + l15 * 2 + 1];
    const float biasC0 = bc1p[w * 32 + l15 * 2];
    const float biasC1 = bc1p[w * 32 + l15 * 2 + 1];
    const float bias2v = bn2[w * 16 + l15];
    const float wc2a = Wc2[w * 32 + l15 * 2];
    const float wc2b = Wc2[w * 32 + l15 * 2 + 1];

    // ---- prologue: stage first tile into buffer 0 ----
    const int t0 = blockIdx.x;
    const int gstep = (int)gridDim.x;
    {
        const int sA = srcg[t0 * 64 + sub], sB = srcg[t0 * 64 + sub + 32];
        const int dA = dstg[t0 * 64 + sub], dB = dstg[t0 * 64 + sub + 32];
        const float dv = dist[t0 * 64 + lane];
        const ushort8 hsa = *(const ushort8*)(hbf + sA * NDIM + c8 * 8);
        const ushort8 hda = *(const ushort8*)(hbf + dA * NDIM + c8 * 8);
        const ushort8 hsb = *(const ushort8*)(hbf + sB * NDIM + c8 * 8);
        const ushort8 hdb = *(const ushort8*)(hbf + dB * NDIM + c8 * 8);
        *(ushort8*)&mlds[0][sub * MSTRIDE + c8 * 8] = hsa;
        *(ushort8*)&mlds[0][sub * MSTRIDE + 64 + c8 * 8] = hda;
        *(ushort8*)&mlds[0][(sub + 32) * MSTRIDE + c8 * 8] = hsb;
        *(ushort8*)&mlds[0][(sub + 32) * MSTRIDE + 64 + c8 * 8] = hdb;
        ushort8 su;
#pragma unroll
        for (int j = 0; j < 8; ++j)
            su[j] = f2bf(silu(fmaf(dv, we1r[j], be1r[j])));
        *(ushort8*)&mlds[0][lane * MSTRIDE + 128 + w * 8] = su;
        if (c8 == 0) { dst_l[0][sub] = dA; dst_l[0][sub + 32] = dB; }
        if (tid < 64) {
            const int us = srcg[t0 * 64 + tid], ud = dstg[t0 * 64 + tid];
            const float ddx = x[us * 3 + 0] - x[ud * 3 + 0];
            const float ddy = x[us * 3 + 1] - x[ud * 3 + 1];
            const float ddz = x[us * 3 + 2] - x[ud * 3 + 2];
            const float len = fmaxf(sqrtf(ddx * ddx + ddy * ddy + ddz * ddz), 1e-8f);
            const float inv = __builtin_amdgcn_rcpf(len);
            unit_l[0][tid] = make_float4(ddx * inv, ddy * inv, ddz * inv, 0.0f);
        }
    }

    int p = 0;
    for (int tile = t0; tile < NTILES; tile += gstep) {
        // ---- prefetch next tile's direct-addressed data ----
        const int tnx = tile + gstep;
        const int tc = (tnx < NTILES) ? tnx : tile;
        const int nsA = srcg[tc * 64 + sub], nsB = srcg[tc * 64 + sub + 32];
        const int ndA = dstg[tc * 64 + sub], ndB = dstg[tc * 64 + sub + 32];
        const float ndv = dist[tc * 64 + lane];

        LGKM_BARRIER();   // mlds[p] / unit_l[p] / dst_l[p] staged

        // ---- GEMM1: [64x160] @ {Wn1', Wc1'} ----
        f32x4 accN[4][2], accC[4][2];
#pragma unroll
        for (int mt = 0; mt < 4; ++mt) {
            accN[mt][0] = (f32x4){biasN0, biasN0, biasN0, biasN0};
            accN[mt][1] = (f32x4){biasN1, biasN1, biasN1, biasN1};
            accC[mt][0] = (f32x4){biasC0, biasC0, biasC0, biasC0};
            accC[mt][1] = (f32x4){biasC1, biasC1, biasC1, biasC1};
        }
#pragma unroll
        for (int kc = 0; kc < 5; ++kc) {
            bf16x8 af[4];
#pragma unroll
            for (int mt = 0; mt < 4; ++mt)
                af[mt] = ld_frag(&mlds[p][(mt * 16 + l15) * MSTRIDE + kc * 32 + quad * 8]);
#pragma unroll
            for (int mt = 0; mt < 4; ++mt) {
#pragma unroll
                for (int nt = 0; nt < 2; ++nt) {
                    accN[mt][nt] = __builtin_amdgcn_mfma_f32_16x16x32_bf16(
                        af[mt], wn1f[kc][nt], accN[mt][nt], 0, 0, 0);
                    accC[mt][nt] = __builtin_amdgcn_mfma_f32_16x16x32_bf16(
                        af[mt], wc1f[kc][nt], accC[mt][nt], 0, 0, 0);
                }
            }
        }

        // ---- issue next tile's h-gathers (idx arrived during GEMM1) ----
        const ushort8 ghsa = *(const ushort8*)(hbf + nsA * NDIM + c8 * 8);
        const ushort8 ghda = *(const ushort8*)(hbf + ndA * NDIM + c8 * 8);
        const ushort8 ghsb = *(const ushort8*)(hbf + nsB * NDIM + c8 * 8);
        const ushort8 ghdb = *(const ushort8*)(hbf + ndB * NDIM + c8 * 8);

        // ---- node path: silu -> paired b32 writes (A-layout) ----
#pragma unroll
        for (int mt = 0; mt < 4; ++mt) {
#pragma unroll
            for (int r = 0; r < 4; ++r) {
                const int row = mt * 16 + quad * 4 + r;
                *(unsigned int*)&hl[row * HSTRIDE + w * 32 + l15 * 2] =
                    pk2bf(silu(accN[mt][0][r]), silu(accN[mt][1][r]));
            }
        }
        LGKM_BARRIER();   // hl ready

        // ---- GEMM2 node + outh atomics (stay in flight past barriers) ----
        f32x4 acc2[4];
#pragma unroll
        for (int mt = 0; mt < 4; ++mt) acc2[mt] = (f32x4){bias2v, bias2v, bias2v, bias2v};
#pragma unroll
        for (int kc = 0; kc < 4; ++kc) {
#pragma unroll
            for (int mt = 0; mt < 4; ++mt) {
                bf16x8 a2 = ld_frag(&hl[(mt * 16 + l15) * HSTRIDE + kc * 32 + quad * 8]);
                acc2[mt] = __builtin_amdgcn_mfma_f32_16x16x32_bf16(a2, wn2f[kc], acc2[mt], 0, 0, 0);
            }
        }
#pragma unroll
        for (int mt = 0; mt < 4; ++mt) {
#pragma unroll
            for (int r = 0; r < 4; ++r) {
                const int el = mt * 16 + quad * 4 + r;
                atomicAdd(outh + dst_l[p][el] * NDIM + w * 16 + l15, acc2[mt][r]);
            }
        }

        // ---- coord path: silu*Wc2 + shfl_xor fold -> per-wave outx atomics ----
        {
            float vals[16];
#pragma unroll
            for (int mt = 0; mt < 4; ++mt)
#pragma unroll
                for (int r = 0; r < 4; ++r)
                    vals[mt * 4 + r] = silu(accC[mt][0][r]) * wc2a +
                                       silu(accC[mt][1][r]) * wc2b;
#pragma unroll
            for (int m = 8; m >= 1; m >>= 1) {
                const bool up = (l15 & m) != 0;
#pragma unroll
                for (int j = 0; j < 8; ++j) {
                    if (j < m) {
                        float send = up ? vals[j] : vals[j + m];
                        float recv = __shfl_xor(send, m, 64);
                        vals[j] = (up ? vals[j + m] : vals[j]) + recv;
                    }
                }
            }
            // vals[0] = this wave's 32-col partial of coord_weight for edge bedge
            const float4 un = unit_l[p][bedge];
            const int dn = dst_l[p][bedge];
            const float cwp = vals[0];
            atomicAdd(outx + dn * 3 + 0, cwp * un.x);
            atomicAdd(outx + dn * 3 + 1, cwp * un.y);
            atomicAdd(outx + dn * 3 + 2, cwp * un.z);
        }

        // ---- stage next tile into buffers [p^1] ----
        *(ushort8*)&mlds[p ^ 1][sub * MSTRIDE + c8 * 8] = ghsa;
        *(ushort8*)&mlds[p ^ 1][sub * MSTRIDE + 64 + c8 * 8] = ghda;
        *(ushort8*)&mlds[p ^ 1][(sub + 32) * MSTRIDE + c8 * 8] = ghsb;
        *(ushort8*)&mlds[p ^ 1][(sub + 32) * MSTRIDE + 64 + c8 * 8] = ghdb;
        {
            ushort8 su;
#pragma unroll
            for (int j = 0; j < 8; ++j)
                su[j] = f2bf(silu(fmaf(ndv, we1r[j], be1r[j])));
            *(ushort8*)&mlds[p ^ 1][lane * MSTRIDE + 128 + w * 8] = su;
        }
        if (c8 == 0) { dst_l[p ^ 1][sub] = ndA; dst_l[p ^ 1][sub + 32] = ndB; }
        if (tid < 64) {
            const int us = srcg[tc * 64 + tid], ud = dstg[tc * 64 + tid];
            const float ddx = x[us * 3 + 0] - x[ud * 3 + 0];
            const float ddy = x[us * 3 + 1] - x[ud * 3 + 1];
            const float ddz = x[us * 3 + 2] - x[ud * 3 + 2];
            const float len = fmaxf(sqrtf(ddx * ddx + ddy * ddy + ddz * ddz), 1e-8f);
            const float inv = __builtin_amdgcn_rcpf(len);
            unit_l[p ^ 1][tid] = make_float4(ddx * inv, ddy * inv, ddz * inv, 0.0f);
        }
        p ^= 1;
    }
}

extern "C" void kernel_launch(void* const* d_in, const int* in_sizes, int n_in,
                              void* d_out, int out_size, void* d_ws, size_t ws_size,
                              hipStream_t stream) {
    const float* h    = (const float*)d_in[0];
    const float* x    = (const float*)d_in[1];
    const int*   ei   = (const int*)d_in[2];
    const float* dist = (const float*)d_in[3];
    const float* We1  = (const float*)d_in[4];
    const float* be1  = (const float*)d_in[5];
    const float* We2  = (const float*)d_in[6];
    const float* be2  = (const float*)d_in[7];
    const float* Wn1  = (const float*)d_in[8];
    const float* bn1  = (const float*)d_in[9];
    const float* Wn2  = (const float*)d_in[10];
    const float* bn2  = (const float*)d_in[11];
    const float* Wc1  = (const float*)d_in[12];
    const float* bc1  = (const float*)d_in[13];
    const float* Wc2  = (const float*)d_in[14];

    unsigned short* hbf  = (unsigned short*)((char*)d_ws + WS_HBF);
    unsigned short* wn1p = (unsigned short*)((char*)d_ws + WS_WN1P);
    unsigned short* wc1p = (unsigned short*)((char*)d_ws + WS_WC1P);
    float* bn1p = (float*)((char*)d_ws + WS_BN1P);
    float* bc1p = (float*)((char*)d_ws + WS_BC1P);

    float* outh = (float*)d_out;
    float* outx = outh + (size_t)NH;

    const int prep_items = 837500 + 20480;
    prep_all<<<(prep_items + 255) / 256, 256, 0, stream>>>(
        h, x, We2, be2, Wn1, bn1, Wc1, bc1,
        (float*)d_out, hbf, wn1p, wc1p, bn1p, bc1p);
    egnn_edges<<<512, 256, 0, stream>>>(hbf, x, ei, ei + NE, dist,
                                        We1, be1, wn1p, bn1p,
                                        Wn2, bn2, wc1p, bc1p, Wc2,
                                        outh, outx);
}